// Round 13
// baseline (92.204 us; speedup 1.0000x reference)
//
#include <hip/hip_runtime.h>

// Head: fused QKV projection + causal attention, MI355X (gfx950)
// B=512, T=256, C=384, D=64. fp32 in/out, bf16 MFMA compute.
// R13 = R12 + amdgpu_waves_per_eu(4,4): pin occupancy to the LDS-feasible
// 4 waves/EU so the allocator uses the full 128-VGPR budget instead of
// targeting 8 waves/EU at 64 VGPR and spilling accB (R12 failure mode).
// 512 blocks x 512 thr (8 waves), LDS 77824 -> 2 blocks/CU, all co-resident.
// Wave w owns two 16-row strips: q-tiles {w, 15-w}. acc = 96 VGPR.
// Phase 1: W per-k-tile stage (12 KB, issue-early/write-late), x global->reg.
// Q stays in registers (pi k-permutation); K stored pi-permuted in LDS.
// Phase 2: kv-chunk=32, P 1KB/wave overlays the Wc region.

typedef short s16x8 __attribute__((ext_vector_type(8)));
typedef float f32x4 __attribute__((ext_vector_type(4)));
typedef float f32x2 __attribute__((ext_vector_type(2)));
typedef unsigned int u32;
typedef unsigned int u32x4 __attribute__((ext_vector_type(4)));
typedef unsigned short u16;
typedef unsigned short u16x4 __attribute__((ext_vector_type(4)));
typedef __bf16 bf16x2 __attribute__((ext_vector_type(2)));

__device__ __forceinline__ u32 cvt2(float x, float y) {
  f32x2 v = {x, y};
  bf16x2 b = __builtin_convertvector(v, bf16x2);
  return __builtin_bit_cast(u32, b);
}
__device__ __forceinline__ u16 f2bf(float f) {
  __bf16 b = (__bf16)f;
  return __builtin_bit_cast(u16, b);
}
__device__ __forceinline__ s16x8 pack8(float4 a, float4 b) {
  u32x4 p = {cvt2(a.x, a.y), cvt2(a.z, a.w), cvt2(b.x, b.y), cvt2(b.z, b.w)};
  return __builtin_bit_cast(s16x8, p);
}
__device__ __forceinline__ s16x8 mk_qf(f32x4 a, f32x4 b) {
  u32x4 p = {cvt2(a[0], a[1]), cvt2(a[2], a[3]), cvt2(b[0], b[1]), cvt2(b[2], b[3])};
  return __builtin_bit_cast(s16x8, p);
}

#define MFMA16 __builtin_amdgcn_mfma_f32_16x16x32_bf16

// LDS (77824 B -> 2 blocks/CU):
//  [0,32768)      K  [256 rows][128 B], pi-permuted, row-swizzled
//  [32768,65536)  V^T[64 dims][512 B]
//  [65536,77824)  Wc k-tile stage [192 rows][64 B] (12 KB) / phase2 P[8][1KB]
#define VTOF 32768
#define WCO  65536

// Phase 2 for one q-tile (R11/R12-verified body, kv-chunk=32).
__device__ __forceinline__ void attn_round(
    const char* __restrict__ smem, char* __restrict__ Pw,
    float* __restrict__ outb, const int qt,
    const s16x8 qf0, const s16x8 qf1, const int g, const int li)
{
  f32x4 o[4];
  float mx[4], ls[4];
#pragma unroll
  for (int r = 0; r < 4; ++r) { mx[r] = -1e30f; ls[r] = 0.f; }
#pragma unroll
  for (int nd = 0; nd < 4; ++nd) o[nd] = (f32x4){0.f, 0.f, 0.f, 0.f};

  const int nc = (qt >> 1) + 1;
#pragma unroll 1
  for (int c = 0; c < nc; ++c) {
    f32x4 s0 = {0.f, 0.f, 0.f, 0.f}, s1 = {0.f, 0.f, 0.f, 0.f};
    const int rb0 = c * 32 + li, rb1 = rb0 + 16;
    s16x8 k00 = *reinterpret_cast<const s16x8*>(
        smem + rb0 * 128 + (((0 + g) ^ (rb0 & 7)) << 4));
    s16x8 k01 = *reinterpret_cast<const s16x8*>(
        smem + rb0 * 128 + (((4 + g) ^ (rb0 & 7)) << 4));
    s16x8 k10 = *reinterpret_cast<const s16x8*>(
        smem + rb1 * 128 + (((0 + g) ^ (rb1 & 7)) << 4));
    s16x8 k11 = *reinterpret_cast<const s16x8*>(
        smem + rb1 * 128 + (((4 + g) ^ (rb1 & 7)) << 4));
    s0 = MFMA16(qf0, k00, s0, 0, 0, 0);
    s0 = MFMA16(qf1, k01, s0, 0, 0, 0);
    s1 = MFMA16(qf0, k10, s1, 0, 0, 0);
    s1 = MFMA16(qf1, k11, s1, 0, 0, 0);

    const bool last = (c == nc - 1);
    float alpha[4];
#pragma unroll
    for (int r = 0; r < 4; ++r) {
      float v0 = s0[r] * 0.125f, v1 = s1[r] * 0.125f;
      if (last) {
        const int qrow = qt * 16 + 4 * g + r;
        if (c * 32 + li > qrow) v0 = -1e30f;
        if (c * 32 + 16 + li > qrow) v1 = -1e30f;
      }
      s0[r] = v0; s1[r] = v1;
      float pm = fmaxf(v0, v1);
      pm = fmaxf(pm, __shfl_xor(pm, 1));
      pm = fmaxf(pm, __shfl_xor(pm, 2));
      pm = fmaxf(pm, __shfl_xor(pm, 4));
      pm = fmaxf(pm, __shfl_xor(pm, 8));
      const float mn = fmaxf(mx[r], pm);
      alpha[r] = __expf(mx[r] - mn);
      mx[r] = mn;
    }
    float ps[4];
#pragma unroll
    for (int r = 0; r < 4; ++r) {
      const float p0 = __expf(s0[r] - mx[r]);
      const float p1 = __expf(s1[r] - mx[r]);
      ps[r] = p0 + p1;
      const int rp = 4 * g + r;
      *reinterpret_cast<u16*>(Pw + rp * 64 + li * 2) = f2bf(p0);
      *reinterpret_cast<u16*>(Pw + rp * 64 + 32 + li * 2) = f2bf(p1);
    }
#pragma unroll
    for (int r = 0; r < 4; ++r) {
      float t = ps[r];
      t += __shfl_xor(t, 1);
      t += __shfl_xor(t, 2);
      t += __shfl_xor(t, 4);
      t += __shfl_xor(t, 8);
      ls[r] = ls[r] * alpha[r] + t;
    }
#pragma unroll
    for (int nd = 0; nd < 4; ++nd)
#pragma unroll
      for (int r = 0; r < 4; ++r) o[nd][r] *= alpha[r];

    __asm__ volatile("s_waitcnt lgkmcnt(0)" ::: "memory");
    s16x8 pa = *reinterpret_cast<const s16x8*>(Pw + li * 64 + g * 16);
#pragma unroll
    for (int nd = 0; nd < 4; ++nd) {
      const int d = nd * 16 + li;
      s16x8 vf = *reinterpret_cast<const s16x8*>(
          smem + VTOF + d * 512 + ((c * 64 + g * 16) ^ ((d & 7) << 4)));
      o[nd] = MFMA16(pa, vf, o[nd], 0, 0, 0);
    }
  }
#pragma unroll
  for (int r = 0; r < 4; ++r) ls[r] = 1.f / ls[r];
#pragma unroll
  for (int nd = 0; nd < 4; ++nd)
#pragma unroll
    for (int r = 0; r < 4; ++r)
      outb[(qt * 16 + 4 * g + r) * 64 + nd * 16 + li] = o[nd][r] * ls[r];
}

__global__ __attribute__((amdgpu_waves_per_eu(4, 4)))
__launch_bounds__(512) void head_kernel(
    const float* __restrict__ x,
    const float* __restrict__ WQ, const float* __restrict__ WK,
    const float* __restrict__ WV, float* __restrict__ out)
{
  __shared__ char smem[77824];
  const int tid = threadIdx.x;
  const int l  = tid & 63;
  const int w  = tid >> 6;                       // 0..7
  const int g  = l >> 4, li = l & 15;
  const long bbase = (long)blockIdx.x * 256;

  const int qtA = w, qtB = 15 - w;
  const int rowA = qtA * 16 + li, rowB = qtB * 16 + li;
  const float* pxA = x + (bbase + rowA) * 384 + g * 8;
  const float* pxB = x + (bbase + rowB) * 384 + g * 8;

  // W staging: 768 chunks of 8 f32; tid covers rows 0..127, tid<256 also 128..191
  const int wrow0 = tid >> 2, wslot = tid & 3;
  const int wrow1 = wrow0 + 128;
  const bool doW2 = (tid < 256);
  const float* wrp0 = ((wrow0 < 64) ? (WQ + wrow0 * 384)
                                    : (WK + (wrow0 - 64) * 384)) + wslot * 8;
  const float* wrp1 = WV + (wrow1 - 128) * 384 + wslot * 8;
  const int wsz0 = (wrow0 >> 1) & 3, wsz1 = (wrow1 >> 1) & 3;
  const int rsz = (li >> 1) & 3;

  float4 wa0, wa1, wb0, wb1;
  // ---- prologue: stage W tile 0 ----
  wa0 = *reinterpret_cast<const float4*>(wrp0);
  wa1 = *reinterpret_cast<const float4*>(wrp0 + 4);
  if (doW2) {
    wb0 = *reinterpret_cast<const float4*>(wrp1);
    wb1 = *reinterpret_cast<const float4*>(wrp1 + 4);
  }
  *reinterpret_cast<s16x8*>(smem + WCO + wrow0 * 64 + ((wslot ^ wsz0) << 4)) =
      pack8(wa0, wa1);
  if (doW2)
    *reinterpret_cast<s16x8*>(smem + WCO + wrow1 * 64 + ((wslot ^ wsz1) << 4)) =
        pack8(wb0, wb1);
  __syncthreads();

  f32x4 accA[12], accB[12];
#pragma unroll
  for (int nt = 0; nt < 12; ++nt) {
    accA[nt] = (f32x4){0.f, 0.f, 0.f, 0.f};
    accB[nt] = (f32x4){0.f, 0.f, 0.f, 0.f};
  }

  // ---- phase 1: 12 k-tiles ----
#pragma unroll 1
  for (int t = 0; t < 12; ++t) {
    if (t < 11) {                                // issue next W tile early (T14)
      wa0 = *reinterpret_cast<const float4*>(wrp0 + (t + 1) * 32);
      wa1 = *reinterpret_cast<const float4*>(wrp0 + (t + 1) * 32 + 4);
      if (doW2) {
        wb0 = *reinterpret_cast<const float4*>(wrp1 + (t + 1) * 32);
        wb1 = *reinterpret_cast<const float4*>(wrp1 + (t + 1) * 32 + 4);
      }
    }
    {
      float4 a0 = *reinterpret_cast<const float4*>(pxA + t * 32);
      float4 a1 = *reinterpret_cast<const float4*>(pxA + t * 32 + 4);
      s16x8 xfA = pack8(a0, a1);
      float4 b0 = *reinterpret_cast<const float4*>(pxB + t * 32);
      float4 b1 = *reinterpret_cast<const float4*>(pxB + t * 32 + 4);
      s16x8 xfB = pack8(b0, b1);
#pragma unroll
      for (int nt = 0; nt < 12; ++nt) {
        s16x8 af = *reinterpret_cast<const s16x8*>(
            smem + WCO + (nt * 16 + li) * 64 + ((g ^ rsz) << 4));
        accA[nt] = MFMA16(af, xfA, accA[nt], 0, 0, 0);
        accB[nt] = MFMA16(af, xfB, accB[nt], 0, 0, 0);
      }
    }
    __syncthreads();                             // Wc reads of tile t done
    if (t < 11) {
      *reinterpret_cast<s16x8*>(smem + WCO + wrow0 * 64 + ((wslot ^ wsz0) << 4)) =
          pack8(wa0, wa1);
      if (doW2)
        *reinterpret_cast<s16x8*>(smem + WCO + wrow1 * 64 + ((wslot ^ wsz1) << 4)) =
            pack8(wb0, wb1);
    }
    __syncthreads();                             // Wc tile t+1 ready
  }

  // ---- epilogue: strip S lane (g,li) holds D[n=16nt+4g+r][row=rowS] ----
  s16x8 qfA0 = mk_qf(accA[0], accA[1]);
  s16x8 qfA1 = mk_qf(accA[2], accA[3]);
  s16x8 qfB0 = mk_qf(accB[0], accB[1]);
  s16x8 qfB1 = mk_qf(accB[2], accB[3]);
#pragma unroll
  for (int mm = 0; mm < 4; ++mm) {               // K, pi-permuted
    const int Eb = 32 * (mm >> 1) + 8 * g + 4 * (mm & 1);
    u16x4 pk;
    pk[0] = f2bf(accA[4 + mm][0]); pk[1] = f2bf(accA[4 + mm][1]);
    pk[2] = f2bf(accA[4 + mm][2]); pk[3] = f2bf(accA[4 + mm][3]);
    *reinterpret_cast<u16x4*>(smem + rowA * 128 +
        (((Eb >> 3) ^ (rowA & 7)) << 4) + (Eb & 7) * 2) = pk;
    pk[0] = f2bf(accB[4 + mm][0]); pk[1] = f2bf(accB[4 + mm][1]);
    pk[2] = f2bf(accB[4 + mm][2]); pk[3] = f2bf(accB[4 + mm][3]);
    *reinterpret_cast<u16x4*>(smem + rowB * 128 +
        (((Eb >> 3) ^ (rowB & 7)) << 4) + (Eb & 7) * 2) = pk;
  }
#pragma unroll
  for (int mm = 0; mm < 4; ++mm)                 // V transposed
#pragma unroll
    for (int r = 0; r < 4; ++r) {
      const int d = mm * 16 + 4 * g + r;
      *reinterpret_cast<u16*>(smem + VTOF + d * 512 +
          ((rowA * 2) ^ ((d & 7) << 4))) = f2bf(accA[8 + mm][r]);
      *reinterpret_cast<u16*>(smem + VTOF + d * 512 +
          ((rowB * 2) ^ ((d & 7) << 4))) = f2bf(accB[8 + mm][r]);
    }
  __syncthreads();                               // K/V ready; Wc region -> P

  // ---- phase 2: wave w handles q-tiles {w, 15-w} (9 chunks total) ----
  char* Pw = smem + WCO + w * 1024;
  float* outb = out + bbase * 64;
  attn_round(smem, Pw, outb, qtA, qfA0, qfA1, g, li);
  attn_round(smem, Pw, outb, qtB, qfB0, qfB1, g, li);
}

extern "C" void kernel_launch(void* const* d_in, const int* in_sizes, int n_in,
                              void* d_out, int out_size, void* d_ws, size_t ws_size,
                              hipStream_t stream) {
  const float* x  = (const float*)d_in[0];
  const float* WQ = (const float*)d_in[1];
  const float* WK = (const float*)d_in[2];
  const float* WV = (const float*)d_in[3];
  float* out = (float*)d_out;

  head_kernel<<<dim3(512), dim3(512), 0, stream>>>(x, WQ, WK, WV, out);
}

// Round 14
// 77.463 us; speedup vs baseline: 1.1903x; 1.1903x over previous
//
#include <hip/hip_runtime.h>

// Head: fused QKV projection + causal attention, MI355X (gfx950)
// B=512, T=256, C=384, D=64. fp32 in/out, bf16 MFMA compute.
// R14 = R12 body with __launch_bounds__(512, 2).
// Allocator heuristic (decoded from R3/R5/R11/R12/R13): targets 2x the
// declared min waves/EU -> VGPR = 512/(2*min). min=2 -> 128 VGPR, which
// covers the ~115 needed (acc 96 + transients) with NO spill, while LDS
// 77824 B still yields 2 co-resident blocks/CU (16 waves = 4/EU).
// 512 blocks x 512 thr; wave w owns strips {w, 15-w} (q-tiles, 9 chunks each).
// Phase 1: W per-k-tile stage (12 KB, issue-early/write-late), x global->reg.
// Q stays in registers (pi k-permutation); K stored pi-permuted in LDS.
// Phase 2: kv-chunk=32, P 1KB/wave overlays the Wc region.

typedef short s16x8 __attribute__((ext_vector_type(8)));
typedef float f32x4 __attribute__((ext_vector_type(4)));
typedef float f32x2 __attribute__((ext_vector_type(2)));
typedef unsigned int u32;
typedef unsigned int u32x4 __attribute__((ext_vector_type(4)));
typedef unsigned short u16;
typedef unsigned short u16x4 __attribute__((ext_vector_type(4)));
typedef __bf16 bf16x2 __attribute__((ext_vector_type(2)));

__device__ __forceinline__ u32 cvt2(float x, float y) {
  f32x2 v = {x, y};
  bf16x2 b = __builtin_convertvector(v, bf16x2);
  return __builtin_bit_cast(u32, b);
}
__device__ __forceinline__ u16 f2bf(float f) {
  __bf16 b = (__bf16)f;
  return __builtin_bit_cast(u16, b);
}
__device__ __forceinline__ s16x8 pack8(float4 a, float4 b) {
  u32x4 p = {cvt2(a.x, a.y), cvt2(a.z, a.w), cvt2(b.x, b.y), cvt2(b.z, b.w)};
  return __builtin_bit_cast(s16x8, p);
}
__device__ __forceinline__ s16x8 mk_qf(f32x4 a, f32x4 b) {
  u32x4 p = {cvt2(a[0], a[1]), cvt2(a[2], a[3]), cvt2(b[0], b[1]), cvt2(b[2], b[3])};
  return __builtin_bit_cast(s16x8, p);
}

#define MFMA16 __builtin_amdgcn_mfma_f32_16x16x32_bf16

// LDS (77824 B -> 2 blocks/CU):
//  [0,32768)      K  [256 rows][128 B], pi-permuted, row-swizzled
//  [32768,65536)  V^T[64 dims][512 B]
//  [65536,77824)  Wc k-tile stage [192 rows][64 B] (12 KB) / phase2 P[8][1KB]
#define VTOF 32768
#define WCO  65536

// Phase 2 for one q-tile (R11/R12-verified body, kv-chunk=32).
__device__ __forceinline__ void attn_round(
    const char* __restrict__ smem, char* __restrict__ Pw,
    float* __restrict__ outb, const int qt,
    const s16x8 qf0, const s16x8 qf1, const int g, const int li)
{
  f32x4 o[4];
  float mx[4], ls[4];
#pragma unroll
  for (int r = 0; r < 4; ++r) { mx[r] = -1e30f; ls[r] = 0.f; }
#pragma unroll
  for (int nd = 0; nd < 4; ++nd) o[nd] = (f32x4){0.f, 0.f, 0.f, 0.f};

  const int nc = (qt >> 1) + 1;
#pragma unroll 1
  for (int c = 0; c < nc; ++c) {
    f32x4 s0 = {0.f, 0.f, 0.f, 0.f}, s1 = {0.f, 0.f, 0.f, 0.f};
    const int rb0 = c * 32 + li, rb1 = rb0 + 16;
    s16x8 k00 = *reinterpret_cast<const s16x8*>(
        smem + rb0 * 128 + (((0 + g) ^ (rb0 & 7)) << 4));
    s16x8 k01 = *reinterpret_cast<const s16x8*>(
        smem + rb0 * 128 + (((4 + g) ^ (rb0 & 7)) << 4));
    s16x8 k10 = *reinterpret_cast<const s16x8*>(
        smem + rb1 * 128 + (((0 + g) ^ (rb1 & 7)) << 4));
    s16x8 k11 = *reinterpret_cast<const s16x8*>(
        smem + rb1 * 128 + (((4 + g) ^ (rb1 & 7)) << 4));
    s0 = MFMA16(qf0, k00, s0, 0, 0, 0);
    s0 = MFMA16(qf1, k01, s0, 0, 0, 0);
    s1 = MFMA16(qf0, k10, s1, 0, 0, 0);
    s1 = MFMA16(qf1, k11, s1, 0, 0, 0);

    const bool last = (c == nc - 1);
    float alpha[4];
#pragma unroll
    for (int r = 0; r < 4; ++r) {
      float v0 = s0[r] * 0.125f, v1 = s1[r] * 0.125f;
      if (last) {
        const int qrow = qt * 16 + 4 * g + r;
        if (c * 32 + li > qrow) v0 = -1e30f;
        if (c * 32 + 16 + li > qrow) v1 = -1e30f;
      }
      s0[r] = v0; s1[r] = v1;
      float pm = fmaxf(v0, v1);
      pm = fmaxf(pm, __shfl_xor(pm, 1));
      pm = fmaxf(pm, __shfl_xor(pm, 2));
      pm = fmaxf(pm, __shfl_xor(pm, 4));
      pm = fmaxf(pm, __shfl_xor(pm, 8));
      const float mn = fmaxf(mx[r], pm);
      alpha[r] = __expf(mx[r] - mn);
      mx[r] = mn;
    }
    float ps[4];
#pragma unroll
    for (int r = 0; r < 4; ++r) {
      const float p0 = __expf(s0[r] - mx[r]);
      const float p1 = __expf(s1[r] - mx[r]);
      ps[r] = p0 + p1;
      const int rp = 4 * g + r;
      *reinterpret_cast<u16*>(Pw + rp * 64 + li * 2) = f2bf(p0);
      *reinterpret_cast<u16*>(Pw + rp * 64 + 32 + li * 2) = f2bf(p1);
    }
#pragma unroll
    for (int r = 0; r < 4; ++r) {
      float t = ps[r];
      t += __shfl_xor(t, 1);
      t += __shfl_xor(t, 2);
      t += __shfl_xor(t, 4);
      t += __shfl_xor(t, 8);
      ls[r] = ls[r] * alpha[r] + t;
    }
#pragma unroll
    for (int nd = 0; nd < 4; ++nd)
#pragma unroll
      for (int r = 0; r < 4; ++r) o[nd][r] *= alpha[r];

    __asm__ volatile("s_waitcnt lgkmcnt(0)" ::: "memory");
    s16x8 pa = *reinterpret_cast<const s16x8*>(Pw + li * 64 + g * 16);
#pragma unroll
    for (int nd = 0; nd < 4; ++nd) {
      const int d = nd * 16 + li;
      s16x8 vf = *reinterpret_cast<const s16x8*>(
          smem + VTOF + d * 512 + ((c * 64 + g * 16) ^ ((d & 7) << 4)));
      o[nd] = MFMA16(pa, vf, o[nd], 0, 0, 0);
    }
  }
#pragma unroll
  for (int r = 0; r < 4; ++r) ls[r] = 1.f / ls[r];
#pragma unroll
  for (int nd = 0; nd < 4; ++nd)
#pragma unroll
    for (int r = 0; r < 4; ++r)
      outb[(qt * 16 + 4 * g + r) * 64 + nd * 16 + li] = o[nd][r] * ls[r];
}

__global__ __launch_bounds__(512, 2) void head_kernel(
    const float* __restrict__ x,
    const float* __restrict__ WQ, const float* __restrict__ WK,
    const float* __restrict__ WV, float* __restrict__ out)
{
  __shared__ char smem[77824];
  const int tid = threadIdx.x;
  const int l  = tid & 63;
  const int w  = tid >> 6;                       // 0..7
  const int g  = l >> 4, li = l & 15;
  const long bbase = (long)blockIdx.x * 256;

  const int qtA = w, qtB = 15 - w;
  const int rowA = qtA * 16 + li, rowB = qtB * 16 + li;
  const float* pxA = x + (bbase + rowA) * 384 + g * 8;
  const float* pxB = x + (bbase + rowB) * 384 + g * 8;

  // W staging: 768 chunks of 8 f32; tid covers rows 0..127, tid<256 also 128..191
  const int wrow0 = tid >> 2, wslot = tid & 3;
  const int wrow1 = wrow0 + 128;
  const bool doW2 = (tid < 256);
  const float* wrp0 = ((wrow0 < 64) ? (WQ + wrow0 * 384)
                                    : (WK + (wrow0 - 64) * 384)) + wslot * 8;
  const float* wrp1 = WV + (wrow1 - 128) * 384 + wslot * 8;
  const int wsz0 = (wrow0 >> 1) & 3, wsz1 = (wrow1 >> 1) & 3;
  const int rsz = (li >> 1) & 3;

  float4 wa0, wa1, wb0, wb1;
  // ---- prologue: stage W tile 0 ----
  wa0 = *reinterpret_cast<const float4*>(wrp0);
  wa1 = *reinterpret_cast<const float4*>(wrp0 + 4);
  if (doW2) {
    wb0 = *reinterpret_cast<const float4*>(wrp1);
    wb1 = *reinterpret_cast<const float4*>(wrp1 + 4);
  }
  *reinterpret_cast<s16x8*>(smem + WCO + wrow0 * 64 + ((wslot ^ wsz0) << 4)) =
      pack8(wa0, wa1);
  if (doW2)
    *reinterpret_cast<s16x8*>(smem + WCO + wrow1 * 64 + ((wslot ^ wsz1) << 4)) =
        pack8(wb0, wb1);
  __syncthreads();

  f32x4 accA[12], accB[12];
#pragma unroll
  for (int nt = 0; nt < 12; ++nt) {
    accA[nt] = (f32x4){0.f, 0.f, 0.f, 0.f};
    accB[nt] = (f32x4){0.f, 0.f, 0.f, 0.f};
  }

  // ---- phase 1: 12 k-tiles ----
#pragma unroll 1
  for (int t = 0; t < 12; ++t) {
    if (t < 11) {                                // issue next W tile early (T14)
      wa0 = *reinterpret_cast<const float4*>(wrp0 + (t + 1) * 32);
      wa1 = *reinterpret_cast<const float4*>(wrp0 + (t + 1) * 32 + 4);
      if (doW2) {
        wb0 = *reinterpret_cast<const float4*>(wrp1 + (t + 1) * 32);
        wb1 = *reinterpret_cast<const float4*>(wrp1 + (t + 1) * 32 + 4);
      }
    }
    {
      float4 a0 = *reinterpret_cast<const float4*>(pxA + t * 32);
      float4 a1 = *reinterpret_cast<const float4*>(pxA + t * 32 + 4);
      s16x8 xfA = pack8(a0, a1);
      float4 b0 = *reinterpret_cast<const float4*>(pxB + t * 32);
      float4 b1 = *reinterpret_cast<const float4*>(pxB + t * 32 + 4);
      s16x8 xfB = pack8(b0, b1);
#pragma unroll
      for (int nt = 0; nt < 12; ++nt) {
        s16x8 af = *reinterpret_cast<const s16x8*>(
            smem + WCO + (nt * 16 + li) * 64 + ((g ^ rsz) << 4));
        accA[nt] = MFMA16(af, xfA, accA[nt], 0, 0, 0);
        accB[nt] = MFMA16(af, xfB, accB[nt], 0, 0, 0);
      }
    }
    __syncthreads();                             // Wc reads of tile t done
    if (t < 11) {
      *reinterpret_cast<s16x8*>(smem + WCO + wrow0 * 64 + ((wslot ^ wsz0) << 4)) =
          pack8(wa0, wa1);
      if (doW2)
        *reinterpret_cast<s16x8*>(smem + WCO + wrow1 * 64 + ((wslot ^ wsz1) << 4)) =
            pack8(wb0, wb1);
    }
    __syncthreads();                             // Wc tile t+1 ready
  }

  // ---- epilogue: strip S lane (g,li) holds D[n=16nt+4g+r][row=rowS] ----
  s16x8 qfA0 = mk_qf(accA[0], accA[1]);
  s16x8 qfA1 = mk_qf(accA[2], accA[3]);
  s16x8 qfB0 = mk_qf(accB[0], accB[1]);
  s16x8 qfB1 = mk_qf(accB[2], accB[3]);
#pragma unroll
  for (int mm = 0; mm < 4; ++mm) {               // K, pi-permuted
    const int Eb = 32 * (mm >> 1) + 8 * g + 4 * (mm & 1);
    u16x4 pk;
    pk[0] = f2bf(accA[4 + mm][0]); pk[1] = f2bf(accA[4 + mm][1]);
    pk[2] = f2bf(accA[4 + mm][2]); pk[3] = f2bf(accA[4 + mm][3]);
    *reinterpret_cast<u16x4*>(smem + rowA * 128 +
        (((Eb >> 3) ^ (rowA & 7)) << 4) + (Eb & 7) * 2) = pk;
    pk[0] = f2bf(accB[4 + mm][0]); pk[1] = f2bf(accB[4 + mm][1]);
    pk[2] = f2bf(accB[4 + mm][2]); pk[3] = f2bf(accB[4 + mm][3]);
    *reinterpret_cast<u16x4*>(smem + rowB * 128 +
        (((Eb >> 3) ^ (rowB & 7)) << 4) + (Eb & 7) * 2) = pk;
  }
#pragma unroll
  for (int mm = 0; mm < 4; ++mm)                 // V transposed
#pragma unroll
    for (int r = 0; r < 4; ++r) {
      const int d = mm * 16 + 4 * g + r;
      *reinterpret_cast<u16*>(smem + VTOF + d * 512 +
          ((rowA * 2) ^ ((d & 7) << 4))) = f2bf(accA[8 + mm][r]);
      *reinterpret_cast<u16*>(smem + VTOF + d * 512 +
          ((rowB * 2) ^ ((d & 7) << 4))) = f2bf(accB[8 + mm][r]);
    }
  __syncthreads();                               // K/V ready; Wc region -> P

  // ---- phase 2: wave w handles q-tiles {w, 15-w} (9 chunks total) ----
  char* Pw = smem + WCO + w * 1024;
  float* outb = out + bbase * 64;
  attn_round(smem, Pw, outb, qtA, qfA0, qfA1, g, li);
  attn_round(smem, Pw, outb, qtB, qfB0, qfB1, g, li);
}

extern "C" void kernel_launch(void* const* d_in, const int* in_sizes, int n_in,
                              void* d_out, int out_size, void* d_ws, size_t ws_size,
                              hipStream_t stream) {
  const float* x  = (const float*)d_in[0];
  const float* WQ = (const float*)d_in[1];
  const float* WK = (const float*)d_in[2];
  const float* WV = (const float*)d_in[3];
  float* out = (float*)d_out;

  head_kernel<<<dim3(512), dim3(512), 0, stream>>>(x, WQ, WK, WV, out);
}